// Round 1
// baseline (268.538 us; speedup 1.0000x reference)
//
#include <hip/hip_runtime.h>
#include <hip/hip_bf16.h>
#include <stdint.h>

#define D 1024
#define NSUP 256
#define ROWS 16384   // 4*4096
#define MB 64        // rows per block in layer kernel
#define LTHREADS 512

typedef __attribute__((__ext_vector_type__(8))) __bf16 bf16x8;
typedef __attribute__((__ext_vector_type__(4))) float f32x4;

__device__ __forceinline__ float bfbits2f(uint32_t b) {
    union { uint32_t u; float f; } c; c.u = b; return c.f;
}

// LDS byte offsets with XOR swizzle (breaks 16-way bank conflict on stride-256B/512B rows)
__device__ __forceinline__ int hnb(int row, int d) {   // hn chunk: [64][128] bf16
    return ((row << 8) + (d << 1)) ^ ((row & 7) << 4);
}
__device__ __forceinline__ int wbyte(int row, int n) { // w: [64][256] bf16
    return ((row << 9) + (n << 1)) ^ ((row & 7) << 4);
}

__global__ void cast_k_kernel(const float* __restrict__ K, __bf16* __restrict__ Kb) {
    int i = (blockIdx.x * 256 + threadIdx.x) * 4;
    float4 v = *(const float4*)(K + i);
    __bf16 o[4] __attribute__((aligned(8)));
    o[0] = (__bf16)v.x; o[1] = (__bf16)v.y; o[2] = (__bf16)v.z; o[3] = (__bf16)v.w;
    *(uint2*)(Kb + i) = *(const uint2*)o;
}

// V [4][256][1024] f32 -> Vt [4][1024][256] bf16
__global__ void transpose_v_kernel(const float* __restrict__ V, __bf16* __restrict__ Vt) {
    __shared__ __bf16 tile[64][72];
    int l = blockIdx.z;
    int d0 = blockIdx.x * 64, n0 = blockIdx.y * 64;
    const float* Vl = V + (size_t)l * NSUP * D;
    __bf16* Vtl = Vt + (size_t)l * D * NSUP;
    for (int j = 0; j < 16; ++j) {
        int idx = j * 256 + threadIdx.x;
        int n_l = idx >> 6, d_l = idx & 63;
        tile[d_l][n_l] = (__bf16)Vl[(size_t)(n0 + n_l) * D + d0 + d_l];
    }
    __syncthreads();
    for (int j = 0; j < 16; ++j) {
        int idx = j * 256 + threadIdx.x;
        int d_l = idx >> 6, n_l = idx & 63;
        Vtl[(size_t)(d0 + d_l) * NSUP + n0 + n_l] = tile[d_l][n_l];
    }
}

__global__ void norms0_kernel(const float* __restrict__ x, float* __restrict__ rn) {
    int row = blockIdx.x * 4 + (threadIdx.x >> 6);
    int lane = threadIdx.x & 63;
    const float4* p = (const float4*)(x + (size_t)row * D);
    float s = 0.f;
    #pragma unroll
    for (int j = 0; j < 4; ++j) {
        float4 v = p[j * 64 + lane];
        s += v.x * v.x + v.y * v.y + v.z * v.z + v.w * v.w;
    }
    #pragma unroll
    for (int off = 1; off < 64; off <<= 1) s += __shfl_xor(s, off);
    if (lane == 0) rn[row] = 1.f / (sqrtf(s) + 1e-9f);
}

// One CleanUpKV layer, fused: normalize -> scores -> softmax -> PV (+ next-layer norms).
// Block: 512 thr (8 waves), 64 rows. Wave w owns score cols [w*32, w*32+32) and PV d-cols [w*128, w*128+128).
template<bool IN_F32, bool OUT_F32>
__global__ __launch_bounds__(LTHREADS)
void layer_kernel(const void* h_in, void* h_out,
                  const __bf16* __restrict__ Kb, const __bf16* __restrict__ Vt,
                  const float* __restrict__ rn_in, float* __restrict__ rn_out) {
    const int tid = threadIdx.x;
    const int lane = tid & 63;
    const int cg = tid >> 6;            // wave id 0..7
    const int llo = lane & 15, lhi = lane >> 4;
    const int row0 = blockIdx.x * MB;

    __shared__ __align__(16) char lds_hn[2][MB * 128 * 2];  // 2 x 16KB, swizzled
    __shared__ __align__(16) char lds_w[MB * NSUP * 2];     // 32KB, swizzled
    __shared__ float red1[MB][8];
    __shared__ float red2[MB][8];
    __shared__ float rnin_s[MB];

    if (tid < MB) rnin_s[tid] = rn_in[row0 + tid];

    const int srow = tid >> 3;          // 0..63
    const int sd = (tid & 7) * 16;      // 0..112

    float stg[16];
    auto load_chunk = [&](int dc) {
        if constexpr (IN_F32) {
            const float4* p = (const float4*)((const float*)h_in + (size_t)(row0 + srow) * D + dc * 128 + sd);
            #pragma unroll
            for (int j = 0; j < 4; ++j) {
                float4 v = p[j];
                stg[4 * j] = v.x; stg[4 * j + 1] = v.y; stg[4 * j + 2] = v.z; stg[4 * j + 3] = v.w;
            }
        } else {
            const uint4* p = (const uint4*)((const uint16_t*)h_in + (size_t)(row0 + srow) * D + dc * 128 + sd);
            #pragma unroll
            for (int j = 0; j < 2; ++j) {
                uint4 u = p[j];
                uint32_t wv[4] = {u.x, u.y, u.z, u.w};
                #pragma unroll
                for (int q = 0; q < 4; ++q) {
                    stg[8 * j + 2 * q]     = bfbits2f(wv[q] << 16);
                    stg[8 * j + 2 * q + 1] = bfbits2f(wv[q] & 0xffff0000u);
                }
            }
        }
    };
    auto write_chunk = [&](int dc) {
        float rn = rnin_s[srow];
        __bf16 tmp[16] __attribute__((aligned(16)));
        #pragma unroll
        for (int j = 0; j < 16; ++j) tmp[j] = (__bf16)(stg[j] * rn);
        char* base = lds_hn[dc & 1];
        *(bf16x8*)(base + hnb(srow, sd))     = *(const bf16x8*)(tmp);
        *(bf16x8*)(base + hnb(srow, sd + 8)) = *(const bf16x8*)(tmp + 8);
    };

    // ---------- Phase A: scores[64x256] = hn @ K^T; wave tile 64 rows x 32 cols ----------
    f32x4 acc[4][2];
    #pragma unroll
    for (int rf = 0; rf < 4; ++rf)
        #pragma unroll
        for (int cf = 0; cf < 2; ++cf)
            acc[rf][cf] = (f32x4){0.f, 0.f, 0.f, 0.f};

    load_chunk(0);
    #pragma unroll 1
    for (int dc = 0; dc < 8; ++dc) {
        __syncthreads();                 // buffer dc&1 free (last used at dc-2)
        write_chunk(dc);
        if (dc < 7) load_chunk(dc + 1);  // prefetch next chunk during MFMA phase
        __syncthreads();
        const char* hb = lds_hn[dc & 1];
        #pragma unroll
        for (int k = 0; k < 4; ++k) {
            bf16x8 a[4];
            #pragma unroll
            for (int rf = 0; rf < 4; ++rf)
                a[rf] = *(const bf16x8*)(hb + hnb(rf * 16 + llo, k * 32 + lhi * 8));
            #pragma unroll
            for (int cf = 0; cf < 2; ++cf) {
                const __bf16* kp = Kb + (size_t)(cg * 32 + cf * 16 + llo) * D + dc * 128 + k * 32 + lhi * 8;
                bf16x8 b = *(const bf16x8*)kp;
                #pragma unroll
                for (int rf = 0; rf < 4; ++rf)
                    acc[rf][cf] = __builtin_amdgcn_mfma_f32_16x16x32_bf16(a[rf], b, acc[rf][cf], 0, 0, 0);
            }
        }
    }

    // ---------- Phase B: softmax over 256 cols (split across 8 waves) ----------
    float rmax[4][4];
    #pragma unroll
    for (int rf = 0; rf < 4; ++rf)
        #pragma unroll
        for (int r = 0; r < 4; ++r) {
            float m = fmaxf(acc[rf][0][r], acc[rf][1][r]);
            #pragma unroll
            for (int off = 1; off < 16; off <<= 1) m = fmaxf(m, __shfl_xor(m, off));
            rmax[rf][r] = m;
        }
    if (llo == 0) {
        #pragma unroll
        for (int rf = 0; rf < 4; ++rf)
            #pragma unroll
            for (int r = 0; r < 4; ++r)
                red1[rf * 16 + lhi * 4 + r][cg] = rmax[rf][r];
    }
    __syncthreads();
    #pragma unroll
    for (int rf = 0; rf < 4; ++rf)
        #pragma unroll
        for (int r = 0; r < 4; ++r) {
            int row = rf * 16 + lhi * 4 + r;
            f32x4 m0 = *(const f32x4*)&red1[row][0];
            f32x4 m1 = *(const f32x4*)&red1[row][4];
            float m = fmaxf(fmaxf(fmaxf(m0[0], m0[1]), fmaxf(m0[2], m0[3])),
                            fmaxf(fmaxf(m1[0], m1[1]), fmaxf(m1[2], m1[3])));
            rmax[rf][r] = m;
        }
    float rsum[4][4];
    #pragma unroll
    for (int rf = 0; rf < 4; ++rf)
        #pragma unroll
        for (int r = 0; r < 4; ++r) {
            float s = 0.f;
            #pragma unroll
            for (int cf = 0; cf < 2; ++cf) {
                float e = exp2f((acc[rf][cf][r] - rmax[rf][r]) * 1.44269504f);
                acc[rf][cf][r] = e;
                s += e;
            }
            #pragma unroll
            for (int off = 1; off < 16; off <<= 1) s += __shfl_xor(s, off);
            rsum[rf][r] = s;
        }
    if (llo == 0) {
        #pragma unroll
        for (int rf = 0; rf < 4; ++rf)
            #pragma unroll
            for (int r = 0; r < 4; ++r)
                red2[rf * 16 + lhi * 4 + r][cg] = rsum[rf][r];
    }
    __syncthreads();
    #pragma unroll
    for (int rf = 0; rf < 4; ++rf)
        #pragma unroll
        for (int r = 0; r < 4; ++r) {
            int row = rf * 16 + lhi * 4 + r;
            f32x4 s0 = *(const f32x4*)&red2[row][0];
            f32x4 s1 = *(const f32x4*)&red2[row][4];
            float s = (s0[0] + s0[1] + s0[2] + s0[3]) + (s1[0] + s1[1] + s1[2] + s1[3]);
            float inv = 1.f / s;
            #pragma unroll
            for (int cf = 0; cf < 2; ++cf) {
                int col = cg * 32 + cf * 16 + llo;
                *(__bf16*)(lds_w + wbyte(row, col)) = (__bf16)(acc[rf][cf][r] * inv);
            }
        }
    __syncthreads();

    // ---------- Phase C: out[64x1024] = w @ V; wave owns d-cols [cg*128, cg*128+128) ----------
    float nacc[4][4];
    #pragma unroll
    for (int rf = 0; rf < 4; ++rf)
        #pragma unroll
        for (int r = 0; r < 4; ++r) nacc[rf][r] = 0.f;

    #pragma unroll 1
    for (int dchunk = 0; dchunk < 2; ++dchunk) {
        f32x4 acc2[4][4];
        #pragma unroll
        for (int rf = 0; rf < 4; ++rf)
            #pragma unroll
            for (int cf = 0; cf < 4; ++cf)
                acc2[rf][cf] = (f32x4){0.f, 0.f, 0.f, 0.f};
        #pragma unroll
        for (int k = 0; k < 8; ++k) {
            bf16x8 a[4];
            #pragma unroll
            for (int rf = 0; rf < 4; ++rf)
                a[rf] = *(const bf16x8*)(lds_w + wbyte(rf * 16 + llo, k * 32 + lhi * 8));
            #pragma unroll
            for (int cf = 0; cf < 4; ++cf) {
                const __bf16* vp = Vt + (size_t)(cg * 128 + dchunk * 64 + cf * 16 + llo) * NSUP + k * 32 + lhi * 8;
                bf16x8 b = *(const bf16x8*)vp;
                #pragma unroll
                for (int rf = 0; rf < 4; ++rf)
                    acc2[rf][cf] = __builtin_amdgcn_mfma_f32_16x16x32_bf16(a[rf], b, acc2[rf][cf], 0, 0, 0);
            }
        }
        #pragma unroll
        for (int rf = 0; rf < 4; ++rf)
            #pragma unroll
            for (int cf = 0; cf < 4; ++cf) {
                int d = cg * 128 + dchunk * 64 + cf * 16 + llo;
                #pragma unroll
                for (int r = 0; r < 4; ++r) {
                    int row = rf * 16 + lhi * 4 + r;
                    float v = acc2[rf][cf][r];
                    size_t idx = (size_t)(row0 + row) * D + d;
                    if constexpr (OUT_F32) {
                        ((float*)h_out)[idx] = v;
                    } else {
                        ((__bf16*)h_out)[idx] = (__bf16)v;
                        nacc[rf][r] += v * v;
                    }
                }
            }
    }

    if constexpr (!OUT_F32) {
        // next-layer row norms: reduce nacc over llo, then over 8 waves via LDS
        #pragma unroll
        for (int rf = 0; rf < 4; ++rf)
            #pragma unroll
            for (int r = 0; r < 4; ++r) {
                float s = nacc[rf][r];
                #pragma unroll
                for (int off = 1; off < 16; off <<= 1) s += __shfl_xor(s, off);
                nacc[rf][r] = s;
            }
        if (llo == 0) {
            #pragma unroll
            for (int rf = 0; rf < 4; ++rf)
                #pragma unroll
                for (int r = 0; r < 4; ++r)
                    red1[rf * 16 + lhi * 4 + r][cg] = nacc[rf][r];
        }
        __syncthreads();
        if (cg == 0 && llo == 0) {
            #pragma unroll
            for (int rf = 0; rf < 4; ++rf)
                #pragma unroll
                for (int r = 0; r < 4; ++r) {
                    int row = rf * 16 + lhi * 4 + r;
                    f32x4 s0 = *(const f32x4*)&red1[row][0];
                    f32x4 s1 = *(const f32x4*)&red1[row][4];
                    float ss = (s0[0] + s0[1] + s0[2] + s0[3]) + (s1[0] + s1[1] + s1[2] + s1[3]);
                    rn_out[row0 + row] = 1.f / (sqrtf(ss) + 1e-9f);
                }
        }
    }
}

extern "C" void kernel_launch(void* const* d_in, const int* in_sizes, int n_in,
                              void* d_out, int out_size, void* d_ws, size_t ws_size,
                              hipStream_t stream) {
    const float* x = (const float*)d_in[0];
    const float* keys = (const float*)d_in[1];
    const float* values = (const float*)d_in[2];
    float* out = (float*)d_out;

    char* ws = (char*)d_ws;
    __bf16* h   = (__bf16*)(ws);                 // 16384*1024*2 = 33554432 B
    __bf16* Kb  = (__bf16*)(ws + 33554432);      // 4*256*1024*2 = 2097152 B
    __bf16* Vt  = (__bf16*)(ws + 35651584);      // 4*1024*256*2 = 2097152 B
    float*  rn0 = (float*)(ws + 37748736);       // 16384*4
    float*  rn1 = (float*)(ws + 37814272);       // 16384*4

    cast_k_kernel<<<1024, 256, 0, stream>>>(keys, Kb);
    transpose_v_kernel<<<dim3(16, 4, 4), 256, 0, stream>>>(values, Vt);
    norms0_kernel<<<4096, 256, 0, stream>>>(x, rn0);

    const int LSTRIDE = NSUP * D;  // 262144 elems per layer for both Kb and Vt
    layer_kernel<true,  false><<<256, LTHREADS, 0, stream>>>(x, h, Kb,               Vt,               rn0, rn1);
    layer_kernel<false, false><<<256, LTHREADS, 0, stream>>>(h, h, Kb + LSTRIDE,     Vt + LSTRIDE,     rn1, rn0);
    layer_kernel<false, false><<<256, LTHREADS, 0, stream>>>(h, h, Kb + 2 * LSTRIDE, Vt + 2 * LSTRIDE, rn0, rn1);
    layer_kernel<false, true ><<<256, LTHREADS, 0, stream>>>(h, out, Kb + 3 * LSTRIDE, Vt + 3 * LSTRIDE, rn1, nullptr);
}